// Round 1
// baseline (214.804 us; speedup 1.0000x reference)
//
#include <hip/hip_runtime.h>

#define LN_EPS 1e-5f

typedef __attribute__((ext_vector_type(8))) short s8vec;   // 8 bf16 = 4 VGPRs (MFMA A/B frag)
typedef __attribute__((ext_vector_type(4))) float f4vec;   // MFMA C/D frag

// ---- workspace layout (bytes); total use = 2,729,984 B (~2.7 MB) ----
#define OFF_WPT   0u         // gamma-folded W_proj, transposed [256][768] bf16
#define OFF_W1T   393216u    // W1 transposed [256][256] bf16
#define OFF_U     524288u    // u[256] f32 : sum_k gamma_k W[k][d]
#define OFF_C     525312u    // c[256] f32 : sum_k beta_k W[k][d] + b_proj[d]
#define OFF_UPART 526336u    // 48*256 f32 partials
#define OFF_VPART 575488u
#define OFF_PM    624640u    // per-chunk softmax max   [1024]
#define OFF_PS    628736u    // per-chunk softmax denom [1024]
#define OFF_PO    632832u    // per-chunk weighted sums [1024][512] f32

__device__ __forceinline__ unsigned short f2bf(float f) {  // RNE fp32->bf16 (finite inputs)
  unsigned int u = __float_as_uint(f);
  u += 0x7fffu + ((u >> 16) & 1u);
  return (unsigned short)(u >> 16);
}
__device__ __forceinline__ float bf2f(unsigned short h) {
  return __uint_as_float(((unsigned int)h) << 16);
}

// K0: fold gamma into W_proj and transpose -> W'T[n][k] bf16; column-sum partials
//     for u,v; transpose W1 -> W1T[e][d] bf16.
__global__ void k0_prep(const float* __restrict__ Wp,
                        const float* __restrict__ gamma,
                        const float* __restrict__ beta,
                        const float* __restrict__ W1,
                        char* __restrict__ ws) {
  const int blk = blockIdx.x;
  const int n = threadIdx.x;
  if (blk < 48) {
    unsigned short* wpt = (unsigned short*)(ws + OFF_WPT);
    const int k0 = blk * 16;
    float up = 0.f, vp = 0.f;
#pragma unroll
    for (int j = 0; j < 16; ++j) {
      const int k = k0 + j;
      const float w = Wp[k * 256 + n];          // coalesced across n
      const float wp = gamma[k] * w;
      up += wp;
      vp += beta[k] * w;
      wpt[n * 768 + k] = f2bf(wp);
    }
    ((float*)(ws + OFF_UPART))[blk * 256 + n] = up;
    ((float*)(ws + OFF_VPART))[blk * 256 + n] = vp;
  } else {
    unsigned short* w1t = (unsigned short*)(ws + OFF_W1T);
    const int d0 = (blk - 48) * 16;
#pragma unroll
    for (int j = 0; j < 16; ++j) {
      const int d = d0 + j;
      w1t[n * 256 + d] = f2bf(W1[d * 256 + n]); // W1T[e][d] = W1[d][e]
    }
  }
}

__global__ void k0_reduce(const float* __restrict__ bproj, char* __restrict__ ws) {
  const int n = threadIdx.x;
  const float* upart = (const float*)(ws + OFF_UPART);
  const float* vpart = (const float*)(ws + OFF_VPART);
  float u = 0.f, v = 0.f;
  for (int i = 0; i < 48; ++i) {
    u += upart[i * 256 + n];
    v += vpart[i * 256 + n];
  }
  ((float*)(ws + OFF_U))[n] = u;
  ((float*)(ws + OFF_C))[n] = v + bproj[n];
}

// K1: per block = 128 rows of one batch element (T%128==0 so never straddles b).
// Phase 1: stream x (sanitize, fp32 row sums for LN, bf16->LDS) fused with
//          MFMA GEMM vs gamma-folded W'T. Phase 2: h@W1 -> tanh -> logits.
// Phase 3: chunk-local softmax partials + weighted pooling partials to ws.
__global__ __launch_bounds__(512)
void k1_main(const float* __restrict__ x,
             const float* __restrict__ b1,
             const float* __restrict__ W2,
             char* __restrict__ ws) {
  __shared__ __align__(16) char sm_h[65536];   // h tile bf16 [128][256], XOR-swizzled
  __shared__ __align__(16) char sm_b[32768];   // B tile bf16 [256][64],  XOR-swizzled
  __shared__ __align__(16) char sm_a[16384];   // A tile bf16 [128][64],  XOR-swizzled
  __shared__ float sm_u[256], sm_c[256], sm_b1[256], sm_w2[256];
  __shared__ float sm_mu[128], sm_inv[128];
  __shared__ float sm_lp[128 * 4];
  __shared__ float sm_lg[128];
  __shared__ float sm_e[128];

  const int tid  = threadIdx.x;
  const int lane = tid & 63;
  const int wid  = tid >> 6;
  const int wr = wid >> 2;       // wave row 0..1  (64 M-rows each)
  const int wc = wid & 3;        // wave col 0..3  (64 N-cols each)
  const int lr = lane & 15;
  const int lq = lane >> 4;

  if (tid < 256) {
    sm_u[tid]  = ((const float*)(ws + OFF_U))[tid];
    sm_c[tid]  = ((const float*)(ws + OFF_C))[tid];
    sm_b1[tid] = b1[tid];
    sm_w2[tid] = W2[tid];
  }

  const int arow = tid >> 2;     // staging: 4 threads per row
  const int aq   = tid & 3;
  const float* xrow = x + (size_t)(blockIdx.x * 128 + arow) * 768 + aq * 16;
  const unsigned short* wpt = (const unsigned short*)(ws + OFF_WPT);
  const int bn = tid >> 1;       // staging B: 2 threads per n-row
  const int bh = tid & 1;

  const f4vec fz = {0.f, 0.f, 0.f, 0.f};
  f4vec acc[4][4];
#pragma unroll
  for (int m = 0; m < 4; ++m)
#pragma unroll
    for (int n = 0; n < 4; ++n) acc[m][n] = fz;

  float s1 = 0.f, s2 = 0.f;

  for (int kk = 0; kk < 768; kk += 64) {
    // ---- stage A: 16 contiguous floats/thread, sanitize, LN sums, bf16 ----
    float v[16];
#pragma unroll
    for (int j = 0; j < 4; ++j) {
      const float4 t = *(const float4*)(xrow + kk + j * 4);
      v[j*4+0] = t.x; v[j*4+1] = t.y; v[j*4+2] = t.z; v[j*4+3] = t.w;
    }
    unsigned int pk[8];
#pragma unroll
    for (int j = 0; j < 16; ++j) {
      float f = v[j];
      if ((__float_as_uint(f) & 0x7f800000u) == 0x7f800000u) f = 0.f;  // nan/inf -> 0
      s1 += f; s2 += f * f;
      const unsigned int hb = f2bf(f);
      if ((j & 1) == 0) pk[j >> 1] = hb; else pk[j >> 1] |= hb << 16;
    }
    {
      const int base = arow * 128 + aq * 32;
      const int sw = (arow & 7) << 4;
      *(int4*)(sm_a + ((base     ) ^ sw)) = make_int4((int)pk[0], (int)pk[1], (int)pk[2], (int)pk[3]);
      *(int4*)(sm_a + ((base + 16) ^ sw)) = make_int4((int)pk[4], (int)pk[5], (int)pk[6], (int)pk[7]);
    }
    // ---- stage B: W'T chunk [256][64] (L2-resident after first pass) ----
    {
      const unsigned short* src = wpt + bn * 768 + kk + bh * 32;
      const int base = bn * 128 + bh * 64;
      const int sw = (bn & 7) << 4;
#pragma unroll
      for (int s = 0; s < 4; ++s) {
        const int4 dv = *(const int4*)(src + s * 8);
        *(int4*)(sm_b + ((base + s * 16) ^ sw)) = dv;
      }
    }
    __syncthreads();
    // ---- MFMA: 2 k-steps of 32, 16 mfma each ----
#pragma unroll
    for (int ks = 0; ks < 2; ++ks) {
      const int kb = (ks * 32 + lq * 8) * 2;
      s8vec af[4], bfv[4];
#pragma unroll
      for (int m = 0; m < 4; ++m) {
        const int row = wr * 64 + m * 16 + lr;
        af[m] = *(const s8vec*)(sm_a + ((row * 128 + kb) ^ ((row & 7) << 4)));
      }
#pragma unroll
      for (int n = 0; n < 4; ++n) {
        const int row = wc * 64 + n * 16 + lr;
        bfv[n] = *(const s8vec*)(sm_b + ((row * 128 + kb) ^ ((row & 7) << 4)));
      }
#pragma unroll
      for (int m = 0; m < 4; ++m)
#pragma unroll
        for (int n = 0; n < 4; ++n)
          acc[m][n] = __builtin_amdgcn_mfma_f32_16x16x32_bf16(af[m], bfv[n], acc[m][n], 0, 0, 0);
    }
    __syncthreads();
  }

  // ---- LN row stats (reduce the 4 staging lanes of each row) ----
  s1 += __shfl_xor(s1, 1); s1 += __shfl_xor(s1, 2);
  s2 += __shfl_xor(s2, 1); s2 += __shfl_xor(s2, 2);
  if (aq == 0) {
    const float mu = s1 * (1.f / 768.f);
    float var = s2 * (1.f / 768.f) - mu * mu;
    var = fmaxf(var, 0.f);
    sm_mu[arow]  = mu;
    sm_inv[arow] = rsqrtf(var + LN_EPS);
  }
  __syncthreads();

  // ---- finalize h = inv*(g - mu*u) + c, write bf16 h tile ----
#pragma unroll
  for (int m = 0; m < 4; ++m) {
#pragma unroll
    for (int i = 0; i < 4; ++i) {
      const int rl = wr * 64 + m * 16 + lq * 4 + i;
      const float mu  = sm_mu[rl];
      const float inv = sm_inv[rl];
      const int sw = (rl & 7) << 4;
#pragma unroll
      for (int n = 0; n < 4; ++n) {
        const int cd = wc * 64 + n * 16 + lr;
        const float h = inv * (acc[m][n][i] - mu * sm_u[cd]) + sm_c[cd];
        *(unsigned short*)(sm_h + ((rl * 512 + cd * 2) ^ sw)) = f2bf(h);
      }
    }
  }
  __syncthreads();

  // ---- phase 2: a = tanh(h@W1 + b1), logits = a.W2 ----
  f4vec acc2[4][4];
#pragma unroll
  for (int m = 0; m < 4; ++m)
#pragma unroll
    for (int n = 0; n < 4; ++n) acc2[m][n] = fz;

  const unsigned short* w1t = (const unsigned short*)(ws + OFF_W1T);
  for (int kk = 0; kk < 256; kk += 64) {
    {
      const unsigned short* src = w1t + bn * 256 + kk + bh * 32;
      const int base = bn * 128 + bh * 64;
      const int sw = (bn & 7) << 4;
#pragma unroll
      for (int s = 0; s < 4; ++s) {
        const int4 dv = *(const int4*)(src + s * 8);
        *(int4*)(sm_b + ((base + s * 16) ^ sw)) = dv;
      }
    }
    __syncthreads();
#pragma unroll
    for (int ks = 0; ks < 2; ++ks) {
      const int kh = (kk + ks * 32 + lq * 8) * 2;  // byte col in h row (512 B)
      const int kb = (ks * 32 + lq * 8) * 2;       // byte col in B row (128 B)
      s8vec af[4], bfv[4];
#pragma unroll
      for (int m = 0; m < 4; ++m) {
        const int row = wr * 64 + m * 16 + lr;
        af[m] = *(const s8vec*)(sm_h + ((row * 512 + kh) ^ ((row & 7) << 4)));
      }
#pragma unroll
      for (int n = 0; n < 4; ++n) {
        const int row = wc * 64 + n * 16 + lr;
        bfv[n] = *(const s8vec*)(sm_b + ((row * 128 + kb) ^ ((row & 7) << 4)));
      }
#pragma unroll
      for (int m = 0; m < 4; ++m)
#pragma unroll
        for (int n = 0; n < 4; ++n)
          acc2[m][n] = __builtin_amdgcn_mfma_f32_16x16x32_bf16(af[m], bfv[n], acc2[m][n], 0, 0, 0);
    }
    __syncthreads();
  }

  float lp[4][4];
#pragma unroll
  for (int m = 0; m < 4; ++m)
#pragma unroll
    for (int i = 0; i < 4; ++i) lp[m][i] = 0.f;

#pragma unroll
  for (int m = 0; m < 4; ++m) {
#pragma unroll
    for (int n = 0; n < 4; ++n) {
      const int cd = wc * 64 + n * 16 + lr;
      const float b1v = sm_b1[cd];
      const float w2v = sm_w2[cd];
#pragma unroll
      for (int i = 0; i < 4; ++i) {
        float z = acc2[m][n][i] + b1v;
        z = fminf(fmaxf(z, -15.f), 15.f);
        const float e2 = __expf(2.f * z);
        const float a = (e2 - 1.f) / (e2 + 1.f);   // tanh
        lp[m][i] += a * w2v;
      }
    }
  }
#pragma unroll
  for (int m = 0; m < 4; ++m) {
#pragma unroll
    for (int i = 0; i < 4; ++i) {
      float t = lp[m][i];
      t += __shfl_xor(t, 1);
      t += __shfl_xor(t, 2);
      t += __shfl_xor(t, 4);
      t += __shfl_xor(t, 8);                      // sum over the 16 col-lanes
      if (lr == 0) sm_lp[(wr * 64 + m * 16 + lq * 4 + i) * 4 + wc] = t;
    }
  }
  __syncthreads();
  if (tid < 128)
    sm_lg[tid] = sm_lp[tid*4+0] + sm_lp[tid*4+1] + sm_lp[tid*4+2] + sm_lp[tid*4+3];
  __syncthreads();

  // ---- phase 3: chunk-local softmax partials + pooled partial vectors ----
  float mx = -1e30f;
  for (int r = 0; r < 128; ++r) mx = fmaxf(mx, sm_lg[r]);   // LDS broadcast, uniform
  if (tid < 128) sm_e[tid] = __expf(sm_lg[tid] - mx);
  __syncthreads();

  {
    const int d = tid & 255;
    const int half = tid >> 8;
    float o = 0.f;
    for (int r = half * 64; r < half * 64 + 64; ++r) {
      const float ev = sm_e[r];
      const unsigned short hb =
          *(const unsigned short*)(sm_h + ((r * 512 + d * 2) ^ ((r & 7) << 4)));
      o += ev * bf2f(hb);
    }
    ((float*)(ws + OFF_PO))[blockIdx.x * 512 + half * 256 + d] = o;
  }
  if (tid == 0) {
    float s = 0.f;
    for (int r = 0; r < 128; ++r) s += sm_e[r];
    ((float*)(ws + OFF_PS))[blockIdx.x] = s;
    ((float*)(ws + OFF_PM))[blockIdx.x] = mx;
  }
}

// K2: combine 16 chunk-partials per batch element (online-softmax merge).
__global__ void k2_combine(const char* __restrict__ ws, float* __restrict__ out) {
  const int b = blockIdx.x;
  const int d = threadIdx.x;
  const float* pm = (const float*)(ws + OFF_PM) + b * 16;
  const float* ps = (const float*)(ws + OFF_PS) + b * 16;
  const float* po = (const float*)(ws + OFF_PO) + (size_t)b * 16 * 512;
  float mx = -1e30f;
  for (int c = 0; c < 16; ++c) mx = fmaxf(mx, pm[c]);
  float num = 0.f, den = 0.f;
  for (int c = 0; c < 16; ++c) {
    const float al = __expf(pm[c] - mx);
    den += al * ps[c];
    num += al * (po[c * 512 + d] + po[c * 512 + 256 + d]);
  }
  out[b * 256 + d] = num / den;
}

extern "C" void kernel_launch(void* const* d_in, const int* in_sizes, int n_in,
                              void* d_out, int out_size, void* d_ws, size_t ws_size,
                              hipStream_t stream) {
  const float* x     = (const float*)d_in[0];
  const float* gamma = (const float*)d_in[1];
  const float* beta  = (const float*)d_in[2];
  const float* Wp    = (const float*)d_in[3];
  const float* bproj = (const float*)d_in[4];
  const float* W1    = (const float*)d_in[5];
  const float* b1    = (const float*)d_in[6];
  const float* W2    = (const float*)d_in[7];
  // d_in[8] = b2 scalar: softmax is shift-invariant -> drops out exactly.
  char* ws = (char*)d_ws;   // needs ~2.73 MB
  float* out = (float*)d_out;

  k0_prep  <<<dim3(64),   dim3(256), 0, stream>>>(Wp, gamma, beta, W1, ws);
  k0_reduce<<<dim3(1),    dim3(256), 0, stream>>>(bproj, ws);
  k1_main  <<<dim3(1024), dim3(512), 0, stream>>>(x, b1, W2, ws);
  k2_combine<<<dim3(64),  dim3(256), 0, stream>>>(ws, out);
}

// Round 2
// 173.345 us; speedup vs baseline: 1.2392x; 1.2392x over previous
//
#include <hip/hip_runtime.h>

#define LN_EPS 1e-5f

typedef __attribute__((ext_vector_type(8))) short s8vec;   // 8 bf16 (MFMA A/B frag)
typedef __attribute__((ext_vector_type(4))) float f4vec;   // MFMA C/D frag

// ---- workspace layout (bytes); total use = 2,738,176 B (~2.7 MB) ----
#define OFF_WPT   0u         // gamma-folded W_projT, PRE-SWIZZLED [12 chunks][256 n][128 B]
#define OFF_W1T   393216u    // W1T, PRE-SWIZZLED [4 chunks][256 e][128 B]
#define OFF_U     524288u    // u[256] f32 : sum_k gamma_k W[k][d]
#define OFF_C     525312u    // c[256] f32 : sum_k beta_k W[k][d] + b_proj[d]
#define OFF_UPART 526336u    // 48*256 f32 partials
#define OFF_VPART 575488u
#define OFF_PM    624640u    // per-chunk softmax max   [2048] f32
#define OFF_PS    632832u    // per-chunk softmax denom [2048] f32
#define OFF_PO    641024u    // per-chunk weighted sums [2048][256] f32

__device__ __forceinline__ unsigned short f2bf(float f) {  // RNE fp32->bf16 (finite inputs)
  unsigned int u = __float_as_uint(f);
  u += 0x7fffu + ((u >> 16) & 1u);
  return (unsigned short)(u >> 16);
}
__device__ __forceinline__ float bf2f(unsigned short h) {
  return __uint_as_float(((unsigned int)h) << 16);
}
__device__ __forceinline__ void gll16(const void* g, void* l) {  // async global->LDS, 16 B/lane
  __builtin_amdgcn_global_load_lds(
      (const __attribute__((address_space(1))) unsigned int*)g,
      (__attribute__((address_space(3))) unsigned int*)l, 16, 0, 0);
}

// K0: fold gamma into W_proj, transpose, and store PRE-INVERSE-SWIZZLED so that a
// linear global_load_lds copy lands as the XOR-swizzled LDS tile (rule: linear
// dest + inverse-swz source + swz read). Same for W1T. Also column-sum partials.
__global__ void k0_prep(const float* __restrict__ Wp,
                        const float* __restrict__ gamma,
                        const float* __restrict__ beta,
                        const float* __restrict__ W1,
                        char* __restrict__ ws) {
  const int blk = blockIdx.x;
  const int n = threadIdx.x;
  const int sw = (n & 7) << 4;
  if (blk < 48) {
    unsigned short* wpt = (unsigned short*)(ws + OFF_WPT);
    const int k0 = blk * 16;
    float up = 0.f, vp = 0.f;
#pragma unroll
    for (int j = 0; j < 16; ++j) {
      const int k = k0 + j;
      const float w = Wp[k * 256 + n];          // coalesced across n
      const float wpv = gamma[k] * w;
      up += wpv;
      vp += beta[k] * w;
      const int c = k >> 6, kc = k & 63;
      wpt[c * 16384 + n * 64 + ((((kc * 2) ^ sw)) >> 1)] = f2bf(wpv);
    }
    ((float*)(ws + OFF_UPART))[blk * 256 + n] = up;
    ((float*)(ws + OFF_VPART))[blk * 256 + n] = vp;
  } else {
    unsigned short* w1t = (unsigned short*)(ws + OFF_W1T);
    const int d0 = (blk - 48) * 16;
#pragma unroll
    for (int j = 0; j < 16; ++j) {
      const int d = d0 + j;
      const int c = d >> 6, dc = d & 63;
      w1t[c * 16384 + n * 64 + ((((dc * 2) ^ sw)) >> 1)] = f2bf(W1[d * 256 + n]);
    }
  }
}

__global__ void k0_reduce(const float* __restrict__ bproj, char* __restrict__ ws) {
  const int n = threadIdx.x;
  const float* upart = (const float*)(ws + OFF_UPART);
  const float* vpart = (const float*)(ws + OFF_VPART);
  float u = 0.f, v = 0.f;
  for (int i = 0; i < 48; ++i) {
    u += upart[i * 256 + n];
    v += vpart[i * 256 + n];
  }
  ((float*)(ws + OFF_U))[n] = u;
  ((float*)(ws + OFF_C))[n] = v + bproj[n];
}

// K1: per block = 64 rows of one batch element. 256 threads (4 waves), 78 KB LDS
// -> 2 blocks/CU so one block's compute phases cover the other's x streaming.
__global__ __launch_bounds__(256, 2)
void k1_main(const float* __restrict__ x,
             const float* __restrict__ b1,
             const float* __restrict__ W2,
             char* __restrict__ ws) {
  __shared__ __align__(16) char sm_h[32768];   // h tile bf16 [64][256], XOR-swizzled
  __shared__ __align__(16) char sm_b[32768];   // B tile bf16 [256][64],  XOR-swizzled
  __shared__ __align__(16) char sm_a[8192];    // A tile bf16 [64][64],   XOR-swizzled
  __shared__ float sm_u[256], sm_c[256], sm_b1[256], sm_w2[256];
  __shared__ float sm_mu[64], sm_inv[64];
  __shared__ float sm_lp[64 * 4];
  __shared__ float sm_lg[64];
  __shared__ float sm_e[64];

  const int tid  = threadIdx.x;
  const int lane = tid & 63;
  const int wid  = tid >> 6;     // wave col 0..3 (64 N-cols each; all waves share all 64 M-rows)
  const int lr = lane & 15;
  const int lq = lane >> 4;

  sm_u[tid]  = ((const float*)(ws + OFF_U))[tid];
  sm_c[tid]  = ((const float*)(ws + OFF_C))[tid];
  sm_b1[tid] = b1[tid];
  sm_w2[tid] = W2[tid];

  const int arow = tid >> 2;     // staging A: 4 threads per row
  const int aq   = tid & 3;
  const float* xrow = x + (size_t)(blockIdx.x * 64 + arow) * 768 + aq * 16;

  const char* bsrc = (const char*)ws + OFF_WPT + wid * 8192 + lane * 16;
  char*       bdst = sm_b + wid * 8192 + lane * 16;

  const f4vec fz = {0.f, 0.f, 0.f, 0.f};
  f4vec acc[4][4];
#pragma unroll
  for (int m = 0; m < 4; ++m)
#pragma unroll
    for (int n = 0; n < 4; ++n) acc[m][n] = fz;

  float s1 = 0.f, s2 = 0.f;
  float4 va[4];
#pragma unroll
  for (int j = 0; j < 4; ++j) va[j] = *(const float4*)(xrow + j * 4);

  for (int c = 0; c < 12; ++c) {
    // ---- B: async linear copy of pre-swizzled W'T chunk (L2-resident) ----
#pragma unroll
    for (int s = 0; s < 8; ++s) gll16(bsrc + c * 32768 + s * 1024, bdst + s * 1024);
    // ---- A: sanitize, LN sums, pack bf16, swizzled LDS write ----
    float v[16];
#pragma unroll
    for (int j = 0; j < 4; ++j) {
      v[4*j+0] = va[j].x; v[4*j+1] = va[j].y; v[4*j+2] = va[j].z; v[4*j+3] = va[j].w;
    }
    unsigned int pk[8];
#pragma unroll
    for (int j = 0; j < 16; ++j) {
      float f = v[j];
      if ((__float_as_uint(f) & 0x7f800000u) == 0x7f800000u) f = 0.f;  // nan/inf -> 0
      s1 += f; s2 += f * f;
      const unsigned int hb = f2bf(f);
      if ((j & 1) == 0) pk[j >> 1] = hb; else pk[j >> 1] |= hb << 16;
    }
    {
      const int base = arow * 128 + aq * 32;
      const int sw = (arow & 7) << 4;
      *(int4*)(sm_a + ((base     ) ^ sw)) = make_int4((int)pk[0], (int)pk[1], (int)pk[2], (int)pk[3]);
      *(int4*)(sm_a + ((base + 16) ^ sw)) = make_int4((int)pk[4], (int)pk[5], (int)pk[6], (int)pk[7]);
    }
    // ---- prefetch next x chunk (latency hides under MFMA-issue + barrier) ----
    if (c < 11) {
#pragma unroll
      for (int j = 0; j < 4; ++j) va[j] = *(const float4*)(xrow + (c + 1) * 64 + j * 4);
    }
    __syncthreads();
    // ---- MFMA: 2 k-steps of 32 ----
#pragma unroll
    for (int ks = 0; ks < 2; ++ks) {
      const int kb = (ks * 32 + lq * 8) * 2;
      s8vec af[4], bfv[4];
#pragma unroll
      for (int m = 0; m < 4; ++m) {
        const int row = m * 16 + lr;
        af[m] = *(const s8vec*)(sm_a + ((row * 128 + kb) ^ ((row & 7) << 4)));
      }
#pragma unroll
      for (int n = 0; n < 4; ++n) {
        const int row = wid * 64 + n * 16 + lr;
        bfv[n] = *(const s8vec*)(sm_b + ((row * 128 + kb) ^ ((row & 7) << 4)));
      }
#pragma unroll
      for (int m = 0; m < 4; ++m)
#pragma unroll
        for (int n = 0; n < 4; ++n)
          acc[m][n] = __builtin_amdgcn_mfma_f32_16x16x32_bf16(af[m], bfv[n], acc[m][n], 0, 0, 0);
    }
    __syncthreads();
  }

  // ---- LN row stats (reduce the 4 staging lanes of each row) ----
  s1 += __shfl_xor(s1, 1); s1 += __shfl_xor(s1, 2);
  s2 += __shfl_xor(s2, 1); s2 += __shfl_xor(s2, 2);
  if (aq == 0) {
    const float mu = s1 * (1.f / 768.f);
    float var = s2 * (1.f / 768.f) - mu * mu;
    var = fmaxf(var, 0.f);
    sm_mu[arow]  = mu;
    sm_inv[arow] = rsqrtf(var + LN_EPS);
  }
  __syncthreads();

  // ---- finalize h = inv*(g - mu*u) + c, write bf16 h tile ----
#pragma unroll
  for (int m = 0; m < 4; ++m) {
#pragma unroll
    for (int i = 0; i < 4; ++i) {
      const int rl = m * 16 + lq * 4 + i;
      const float mu  = sm_mu[rl];
      const float inv = sm_inv[rl];
      const int sw = (rl & 7) << 4;
#pragma unroll
      for (int n = 0; n < 4; ++n) {
        const int cd = wid * 64 + n * 16 + lr;
        const float h = inv * (acc[m][n][i] - mu * sm_u[cd]) + sm_c[cd];
        *(unsigned short*)(sm_h + ((rl * 512 + cd * 2) ^ sw)) = f2bf(h);
      }
    }
  }
  __syncthreads();

  // ---- phase 2: a = tanh(h@W1 + b1), logits = a.W2 ----
  f4vec acc2[4][4];
#pragma unroll
  for (int m = 0; m < 4; ++m)
#pragma unroll
    for (int n = 0; n < 4; ++n) acc2[m][n] = fz;

  const char* b2src = (const char*)ws + OFF_W1T + wid * 8192 + lane * 16;
  for (int c = 0; c < 4; ++c) {
#pragma unroll
    for (int s = 0; s < 8; ++s) gll16(b2src + c * 32768 + s * 1024, bdst + s * 1024);
    __syncthreads();
#pragma unroll
    for (int ks = 0; ks < 2; ++ks) {
      const int kh = (c * 64 + ks * 32 + lq * 8) * 2;  // byte col in h row (512 B)
      const int kb = (ks * 32 + lq * 8) * 2;           // byte col in B row (128 B)
      s8vec af[4], bfv[4];
#pragma unroll
      for (int m = 0; m < 4; ++m) {
        const int row = m * 16 + lr;
        af[m] = *(const s8vec*)(sm_h + ((row * 512 + kh) ^ ((row & 7) << 4)));
      }
#pragma unroll
      for (int n = 0; n < 4; ++n) {
        const int row = wid * 64 + n * 16 + lr;
        bfv[n] = *(const s8vec*)(sm_b + ((row * 128 + kb) ^ ((row & 7) << 4)));
      }
#pragma unroll
      for (int m = 0; m < 4; ++m)
#pragma unroll
        for (int n = 0; n < 4; ++n)
          acc2[m][n] = __builtin_amdgcn_mfma_f32_16x16x32_bf16(af[m], bfv[n], acc2[m][n], 0, 0, 0);
    }
    __syncthreads();
  }

  float lp[4][4];
#pragma unroll
  for (int m = 0; m < 4; ++m)
#pragma unroll
    for (int i = 0; i < 4; ++i) lp[m][i] = 0.f;

#pragma unroll
  for (int m = 0; m < 4; ++m) {
#pragma unroll
    for (int n = 0; n < 4; ++n) {
      const int cd = wid * 64 + n * 16 + lr;
      const float b1v = sm_b1[cd];
      const float w2v = sm_w2[cd];
#pragma unroll
      for (int i = 0; i < 4; ++i) {
        float z = acc2[m][n][i] + b1v;
        z = fminf(fmaxf(z, -15.f), 15.f);
        const float e2 = __expf(2.f * z);
        const float a = (e2 - 1.f) / (e2 + 1.f);   // tanh
        lp[m][i] += a * w2v;
      }
    }
  }
#pragma unroll
  for (int m = 0; m < 4; ++m) {
#pragma unroll
    for (int i = 0; i < 4; ++i) {
      float t = lp[m][i];
      t += __shfl_xor(t, 1);
      t += __shfl_xor(t, 2);
      t += __shfl_xor(t, 4);
      t += __shfl_xor(t, 8);                      // sum over the 16 col-lanes
      if (lr == 0) sm_lp[(m * 16 + lq * 4 + i) * 4 + wid] = t;
    }
  }
  __syncthreads();
  if (tid < 64)
    sm_lg[tid] = sm_lp[tid*4+0] + sm_lp[tid*4+1] + sm_lp[tid*4+2] + sm_lp[tid*4+3];
  __syncthreads();

  // ---- phase 3: chunk-local softmax partials + pooled partial vector ----
  float mx = -1e30f;
  for (int r = 0; r < 64; ++r) mx = fmaxf(mx, sm_lg[r]);   // LDS broadcast, uniform
  if (tid < 64) sm_e[tid] = __expf(sm_lg[tid] - mx);
  __syncthreads();

  {
    const int d = tid;
    float o = 0.f;
    for (int r = 0; r < 64; ++r) {
      const float ev = sm_e[r];
      const unsigned short hb =
          *(const unsigned short*)(sm_h + ((r * 512 + d * 2) ^ ((r & 7) << 4)));
      o += ev * bf2f(hb);
    }
    ((float*)(ws + OFF_PO))[blockIdx.x * 256 + d] = o;
  }
  if (tid == 0) {
    float s = 0.f;
    for (int r = 0; r < 64; ++r) s += sm_e[r];
    ((float*)(ws + OFF_PS))[blockIdx.x] = s;
    ((float*)(ws + OFF_PM))[blockIdx.x] = mx;
  }
}

// K2: combine 32 chunk-partials per batch element (online-softmax merge).
__global__ void k2_combine(const char* __restrict__ ws, float* __restrict__ out) {
  const int b = blockIdx.x;
  const int d = threadIdx.x;
  const float* pm = (const float*)(ws + OFF_PM) + b * 32;
  const float* ps = (const float*)(ws + OFF_PS) + b * 32;
  const float* po = (const float*)(ws + OFF_PO) + (size_t)b * 32 * 256;
  float mx = -1e30f;
  for (int c = 0; c < 32; ++c) mx = fmaxf(mx, pm[c]);
  float num = 0.f, den = 0.f;
  for (int c = 0; c < 32; ++c) {
    const float al = __expf(pm[c] - mx);
    den += al * ps[c];
    num += al * po[c * 256 + d];
  }
  out[b * 256 + d] = num / den;
}

extern "C" void kernel_launch(void* const* d_in, const int* in_sizes, int n_in,
                              void* d_out, int out_size, void* d_ws, size_t ws_size,
                              hipStream_t stream) {
  const float* x     = (const float*)d_in[0];
  const float* gamma = (const float*)d_in[1];
  const float* beta  = (const float*)d_in[2];
  const float* Wp    = (const float*)d_in[3];
  const float* bproj = (const float*)d_in[4];
  const float* W1    = (const float*)d_in[5];
  const float* b1    = (const float*)d_in[6];
  const float* W2    = (const float*)d_in[7];
  // d_in[8] = b2 scalar: softmax is shift-invariant -> drops out exactly.
  char* ws = (char*)d_ws;   // needs ~2.74 MB
  float* out = (float*)d_out;

  k0_prep   <<<dim3(64),   dim3(256), 0, stream>>>(Wp, gamma, beta, W1, ws);
  k0_reduce <<<dim3(1),    dim3(256), 0, stream>>>(bproj, ws);
  k1_main   <<<dim3(2048), dim3(256), 0, stream>>>(x, b1, W2, ws);
  k2_combine<<<dim3(64),   dim3(256), 0, stream>>>(ws, out);
}

// Round 4
// 170.382 us; speedup vs baseline: 1.2607x; 1.0174x over previous
//
#include <hip/hip_runtime.h>

#define LN_EPS 1e-5f

typedef __attribute__((ext_vector_type(8))) short s8vec;   // 8 bf16 (MFMA A/B frag)
typedef __attribute__((ext_vector_type(4))) float f4vec;   // MFMA C/D frag

// ---- workspace layout (bytes); total use = 2,738,176 B (~2.7 MB) ----
#define OFF_WPT   0u         // gamma-folded W_projT, PRE-SWIZZLED [12 chunks][256 n][128 B]
#define OFF_W1T   393216u    // W1T, PRE-SWIZZLED [4 chunks][256 e][128 B]
#define OFF_U     524288u    // u[256] f32 : sum_k gamma_k W[k][d]
#define OFF_C     525312u    // c[256] f32 : sum_k beta_k W[k][d] + b_proj[d]
#define OFF_UPART 526336u    // 48*256 f32 partials
#define OFF_VPART 575488u
#define OFF_PM    624640u    // per-chunk softmax max   [2048] f32
#define OFF_PS    632832u    // per-chunk softmax denom [2048] f32
#define OFF_PO    641024u    // per-chunk weighted sums [2048][256] f32

// Raw barrier + counted waits (T3/T4): keep x-prefetch loads in flight ACROSS
// the barrier; only drain what the next phase actually needs.
#define BAR()     asm volatile("s_barrier" ::: "memory")
#define WAIT_V4() asm volatile("s_waitcnt vmcnt(4) lgkmcnt(0)" ::: "memory")
#define WAIT_V0() asm volatile("s_waitcnt vmcnt(0) lgkmcnt(0)" ::: "memory")
#define WAIT_L0() asm volatile("s_waitcnt lgkmcnt(0)" ::: "memory")
// Issue-order fence: counted vmcnt is only valid if the emitted issue order is
// [gll16 ... (old) | va-prefetch (new)]. gll16 (LDS store) and the va loads
// (VGPR loads) provably don't alias, so without this the compiler may hoist
// the va loads above the gll16s and vmcnt(4) would leave gll16s in flight
// across the barrier (round-3 race, absmax 1.95e-3).
#define ORDER_FENCE() do { asm volatile("" ::: "memory"); \
                           __builtin_amdgcn_sched_barrier(0); } while (0)

__device__ __forceinline__ unsigned short f2bf(float f) {  // RNE fp32->bf16 (finite inputs)
  unsigned int u = __float_as_uint(f);
  u += 0x7fffu + ((u >> 16) & 1u);
  return (unsigned short)(u >> 16);
}
__device__ __forceinline__ float bf2f(unsigned short h) {
  return __uint_as_float(((unsigned int)h) << 16);
}
__device__ __forceinline__ void gll16(const void* g, void* l) {  // async global->LDS, 16 B/lane
  __builtin_amdgcn_global_load_lds(
      (const __attribute__((address_space(1))) unsigned int*)g,
      (__attribute__((address_space(3))) unsigned int*)l, 16, 0, 0);
}

// K0: fold gamma into W_proj, transpose, store PRE-INVERSE-SWIZZLED so a linear
// global_load_lds copy lands as the XOR-swizzled LDS tile. Same for W1T.
__global__ void k0_prep(const float* __restrict__ Wp,
                        const float* __restrict__ gamma,
                        const float* __restrict__ beta,
                        const float* __restrict__ W1,
                        char* __restrict__ ws) {
  const int blk = blockIdx.x;
  const int n = threadIdx.x;
  const int sw = (n & 7) << 4;
  if (blk < 48) {
    unsigned short* wpt = (unsigned short*)(ws + OFF_WPT);
    const int k0 = blk * 16;
    float up = 0.f, vp = 0.f;
#pragma unroll
    for (int j = 0; j < 16; ++j) {
      const int k = k0 + j;
      const float w = Wp[k * 256 + n];          // coalesced across n
      const float wpv = gamma[k] * w;
      up += wpv;
      vp += beta[k] * w;
      const int c = k >> 6, kc = k & 63;
      wpt[c * 16384 + n * 64 + ((((kc * 2) ^ sw)) >> 1)] = f2bf(wpv);
    }
    ((float*)(ws + OFF_UPART))[blk * 256 + n] = up;
    ((float*)(ws + OFF_VPART))[blk * 256 + n] = vp;
  } else {
    unsigned short* w1t = (unsigned short*)(ws + OFF_W1T);
    const int d0 = (blk - 48) * 16;
#pragma unroll
    for (int j = 0; j < 16; ++j) {
      const int d = d0 + j;
      const int c = d >> 6, dc = d & 63;
      w1t[c * 16384 + n * 64 + ((((dc * 2) ^ sw)) >> 1)] = f2bf(W1[d * 256 + n]);
    }
  }
}

__global__ void k0_reduce(const float* __restrict__ bproj, char* __restrict__ ws) {
  const int n = threadIdx.x;
  const float* upart = (const float*)(ws + OFF_UPART);
  const float* vpart = (const float*)(ws + OFF_VPART);
  float u = 0.f, v = 0.f;
  for (int i = 0; i < 48; ++i) {
    u += upart[i * 256 + n];
    v += vpart[i * 256 + n];
  }
  ((float*)(ws + OFF_U))[n] = u;
  ((float*)(ws + OFF_C))[n] = v + bproj[n];
}

// K1: per block = 64 rows of one batch element. 256 threads, ~80 KB LDS ->
// 2 blocks/CU. Counted-vmcnt barriers keep the x prefetch pipeline live.
__global__ __launch_bounds__(256, 2)
void k1_main(const float* __restrict__ x,
             const float* __restrict__ b1,
             const float* __restrict__ W2,
             char* __restrict__ ws) {
  __shared__ __align__(16) char sm_h[32768];   // h tile bf16 [64][256], XOR-swizzled
  __shared__ __align__(16) char sm_b[32768];   // B tile bf16 [256][64],  XOR-swizzled
  __shared__ __align__(16) char sm_a[8192];    // A tile bf16 [64][64],   XOR-swizzled
  __shared__ float sm_u[256], sm_c[256], sm_b1[256], sm_w2[256];
  __shared__ float sm_mu[64], sm_inv[64];
  __shared__ float sm_lp[64 * 4];
  __shared__ float sm_lg[64];
  __shared__ float sm_e[64];

  const int tid  = threadIdx.x;
  const int lane = tid & 63;
  const int wid  = tid >> 6;     // wave col 0..3 (64 N-cols each; waves share all 64 M-rows)
  const int lr = lane & 15;
  const int lq = lane >> 4;

  sm_u[tid]  = ((const float*)(ws + OFF_U))[tid];
  sm_c[tid]  = ((const float*)(ws + OFF_C))[tid];
  sm_b1[tid] = b1[tid];
  sm_w2[tid] = W2[tid];

  const int arow = tid >> 2;     // staging A: 4 threads per row
  const int aq   = tid & 3;
  const float* xrow = x + (size_t)(blockIdx.x * 64 + arow) * 768 + aq * 16;

  const char* bsrc  = (const char*)ws + OFF_WPT + wid * 8192 + lane * 16;
  const char* b2src = (const char*)ws + OFF_W1T + wid * 8192 + lane * 16;
  char*       bdst  = sm_b + wid * 8192 + lane * 16;

  const f4vec fz = {0.f, 0.f, 0.f, 0.f};
  f4vec acc[4][4];
#pragma unroll
  for (int m = 0; m < 4; ++m)
#pragma unroll
    for (int n = 0; n < 4; ++n) acc[m][n] = fz;

  float s1 = 0.f, s2 = 0.f;
  float4 vaA[4], vaB[4];                 // ping-pong x prefetch, distance 2
#pragma unroll
  for (int j = 0; j < 4; ++j) vaA[j] = *(const float4*)(xrow + 0 * 64 + j * 4);
#pragma unroll
  for (int j = 0; j < 4; ++j) vaB[j] = *(const float4*)(xrow + 1 * 64 + j * 4);

  // Phase-1 iteration body. va: chunk c (consumed, then refilled with c+2).
  auto p1body = [&](int c, float4 (&va)[4], bool pf) {
    // B: async linear copy of pre-swizzled W'T chunk (L2-resident)
#pragma unroll
    for (int s = 0; s < 8; ++s) gll16(bsrc + c * 32768 + s * 1024, bdst + s * 1024);
    ORDER_FENCE();                       // gll16s are the OLDEST vmem ops from here on
    // A: sanitize, LN sums, pack bf16, swizzled LDS write
    float v[16];
#pragma unroll
    for (int j = 0; j < 4; ++j) {
      v[4*j+0] = va[j].x; v[4*j+1] = va[j].y; v[4*j+2] = va[j].z; v[4*j+3] = va[j].w;
    }
    unsigned int pk[8];
#pragma unroll
    for (int j = 0; j < 16; ++j) {
      float f = v[j];
      if ((__float_as_uint(f) & 0x7f800000u) == 0x7f800000u) f = 0.f;  // nan/inf -> 0
      s1 += f; s2 += f * f;
      const unsigned int hb = f2bf(f);
      if ((j & 1) == 0) pk[j >> 1] = hb; else pk[j >> 1] |= hb << 16;
    }
    {
      const int base = arow * 128 + aq * 32;
      const int sw = (arow & 7) << 4;
      *(int4*)(sm_a + ((base     ) ^ sw)) = make_int4((int)pk[0], (int)pk[1], (int)pk[2], (int)pk[3]);
      *(int4*)(sm_a + ((base + 16) ^ sw)) = make_int4((int)pk[4], (int)pk[5], (int)pk[6], (int)pk[7]);
    }
    // prefetch chunk c+2 into the SAME named array (stays in flight across barrier)
    if (pf) {
#pragma unroll
      for (int j = 0; j < 4; ++j) va[j] = *(const float4*)(xrow + (c + 2) * 64 + j * 4);
    }
    if (pf) WAIT_V4(); else WAIT_V0();   // B-gll + A ds_writes drained; x prefetch flying
    BAR();
    // MFMA: 2 k-steps of 32
#pragma unroll
    for (int ks = 0; ks < 2; ++ks) {
      const int kb = (ks * 32 + lq * 8) * 2;
      s8vec af[4], bfv[4];
#pragma unroll
      for (int m = 0; m < 4; ++m) {
        const int row = m * 16 + lr;
        af[m] = *(const s8vec*)(sm_a + ((row * 128 + kb) ^ ((row & 7) << 4)));
      }
#pragma unroll
      for (int n = 0; n < 4; ++n) {
        const int row = wid * 64 + n * 16 + lr;
        bfv[n] = *(const s8vec*)(sm_b + ((row * 128 + kb) ^ ((row & 7) << 4)));
      }
#pragma unroll
      for (int m = 0; m < 4; ++m)
#pragma unroll
        for (int n = 0; n < 4; ++n)
          acc[m][n] = __builtin_amdgcn_mfma_f32_16x16x32_bf16(af[m], bfv[n], acc[m][n], 0, 0, 0);
    }
    BAR();                               // reads retired (reg-consumed) before next writes
  };

  for (int cc = 0; cc < 12; cc += 2) {
    p1body(cc,     vaA, cc + 2 < 12);
    p1body(cc + 1, vaB, cc + 3 < 12);
  }

  // ---- LN row stats (reduce the 4 staging lanes of each row) ----
  s1 += __shfl_xor(s1, 1); s1 += __shfl_xor(s1, 2);
  s2 += __shfl_xor(s2, 1); s2 += __shfl_xor(s2, 2);
  if (aq == 0) {
    const float mu = s1 * (1.f / 768.f);
    float var = s2 * (1.f / 768.f) - mu * mu;
    var = fmaxf(var, 0.f);
    sm_mu[arow]  = mu;
    sm_inv[arow] = rsqrtf(var + LN_EPS);
  }
  // issue phase-2 chunk-0 B load early: hides L2 latency under h-finalize VALU
#pragma unroll
  for (int s = 0; s < 8; ++s) gll16(b2src + s * 1024, bdst + s * 1024);
  WAIT_L0();                             // sm_mu/sm_inv writes drained (gll still flying)
  BAR();

  // ---- finalize h = inv*(g - mu*u) + c, write bf16 h tile ----
#pragma unroll
  for (int m = 0; m < 4; ++m) {
#pragma unroll
    for (int i = 0; i < 4; ++i) {
      const int rl = m * 16 + lq * 4 + i;
      const float mu  = sm_mu[rl];
      const float inv = sm_inv[rl];
      const int sw = (rl & 7) << 4;
#pragma unroll
      for (int n = 0; n < 4; ++n) {
        const int cd = wid * 64 + n * 16 + lr;
        const float h = inv * (acc[m][n][i] - mu * sm_u[cd]) + sm_c[cd];
        *(unsigned short*)(sm_h + ((rl * 512 + cd * 2) ^ sw)) = f2bf(h);
      }
    }
  }
  WAIT_V0();                             // B0 landed + sm_h writes drained
  BAR();

  // ---- phase 2: a = tanh(h@W1 + b1), logits = a.W2 ----
  f4vec acc2[4][4];
#pragma unroll
  for (int m = 0; m < 4; ++m)
#pragma unroll
    for (int n = 0; n < 4; ++n) acc2[m][n] = fz;

  for (int c = 0; c < 4; ++c) {
    // read ALL fragments for chunk c into regs first, so the next B chunk's
    // global_load_lds can overlap the MFMA burst (single sm_b buffer).
    s8vec af[2][4], bfv[2][4];
#pragma unroll
    for (int ks = 0; ks < 2; ++ks) {
      const int kh = (c * 64 + ks * 32 + lq * 8) * 2;  // byte col in h row (512 B)
      const int kb = (ks * 32 + lq * 8) * 2;           // byte col in B row (128 B)
#pragma unroll
      for (int m = 0; m < 4; ++m) {
        const int row = m * 16 + lr;
        af[ks][m] = *(const s8vec*)(sm_h + ((row * 512 + kh) ^ ((row & 7) << 4)));
      }
#pragma unroll
      for (int n = 0; n < 4; ++n) {
        const int row = wid * 64 + n * 16 + lr;
        bfv[ks][n] = *(const s8vec*)(sm_b + ((row * 128 + kb) ^ ((row & 7) << 4)));
      }
    }
    WAIT_L0();                           // frags in regs; sm_b free to overwrite
    BAR();
    if (c < 3) {
#pragma unroll
      for (int s = 0; s < 8; ++s) gll16(b2src + (c + 1) * 32768 + s * 1024, bdst + s * 1024);
    }
#pragma unroll
    for (int ks = 0; ks < 2; ++ks)
#pragma unroll
      for (int m = 0; m < 4; ++m)
#pragma unroll
        for (int n = 0; n < 4; ++n)
          acc2[m][n] = __builtin_amdgcn_mfma_f32_16x16x32_bf16(af[ks][m], bfv[ks][n], acc2[m][n], 0, 0, 0);
    if (c < 3) WAIT_V0();                // next B chunk landed
    BAR();
  }

  float lp[4][4];
#pragma unroll
  for (int m = 0; m < 4; ++m)
#pragma unroll
    for (int i = 0; i < 4; ++i) lp[m][i] = 0.f;

#pragma unroll
  for (int m = 0; m < 4; ++m) {
#pragma unroll
    for (int n = 0; n < 4; ++n) {
      const int cd = wid * 64 + n * 16 + lr;
      const float b1v = sm_b1[cd];
      const float w2v = sm_w2[cd];
#pragma unroll
      for (int i = 0; i < 4; ++i) {
        float z = acc2[m][n][i] + b1v;
        z = fminf(fmaxf(z, -15.f), 15.f);
        const float e2 = __expf(2.f * z);
        const float a = (e2 - 1.f) / (e2 + 1.f);   // tanh
        lp[m][i] += a * w2v;
      }
    }
  }
#pragma unroll
  for (int m = 0; m < 4; ++m) {
#pragma unroll
    for (int i = 0; i < 4; ++i) {
      float t = lp[m][i];
      t += __shfl_xor(t, 1);
      t += __shfl_xor(t, 2);
      t += __shfl_xor(t, 4);
      t += __shfl_xor(t, 8);                      // sum over the 16 col-lanes
      if (lr == 0) sm_lp[(m * 16 + lq * 4 + i) * 4 + wid] = t;
    }
  }
  __syncthreads();
  if (tid < 64)
    sm_lg[tid] = sm_lp[tid*4+0] + sm_lp[tid*4+1] + sm_lp[tid*4+2] + sm_lp[tid*4+3];
  __syncthreads();

  // ---- phase 3: chunk-local softmax partials + pooled partial vector ----
  float mx = -1e30f;
  for (int r = 0; r < 64; ++r) mx = fmaxf(mx, sm_lg[r]);   // LDS broadcast, uniform
  if (tid < 64) sm_e[tid] = __expf(sm_lg[tid] - mx);
  __syncthreads();

  {
    const int d = tid;
    float o = 0.f;
    for (int r = 0; r < 64; ++r) {
      const float ev = sm_e[r];
      const unsigned short hb =
          *(const unsigned short*)(sm_h + ((r * 512 + d * 2) ^ ((r & 7) << 4)));
      o += ev * bf2f(hb);
    }
    ((float*)(ws + OFF_PO))[blockIdx.x * 256 + d] = o;
  }
  if (tid == 0) {
    float s = 0.f;
    for (int r = 0; r < 64; ++r) s += sm_e[r];
    ((float*)(ws + OFF_PS))[blockIdx.x] = s;
    ((float*)(ws + OFF_PM))[blockIdx.x] = mx;
  }
}

// K2: combine 32 chunk-partials per batch element (online-softmax merge).
__global__ void k2_combine(const char* __restrict__ ws, float* __restrict__ out) {
  const int b = blockIdx.x;
  const int d = threadIdx.x;
  const float* pm = (const float*)(ws + OFF_PM) + b * 32;
  const float* ps = (const float*)(ws + OFF_PS) + b * 32;
  const float* po = (const float*)(ws + OFF_PO) + (size_t)b * 32 * 256;
  float mx = -1e30f;
  for (int c = 0; c < 32; ++c) mx = fmaxf(mx, pm[c]);
  float num = 0.f, den = 0.f;
  for (int c = 0; c < 32; ++c) {
    const float al = __expf(pm[c] - mx);
    den += al * ps[c];
    num += al * po[c * 256 + d];
  }
  out[b * 256 + d] = num / den;
}

extern "C" void kernel_launch(void* const* d_in, const int* in_sizes, int n_in,
                              void* d_out, int out_size, void* d_ws, size_t ws_size,
                              hipStream_t stream) {
  const float* x     = (const float*)d_in[0];
  const float* gamma = (const float*)d_in[1];
  const float* beta  = (const float*)d_in[2];
  const float* Wp    = (const float*)d_in[3];
  const float* bproj = (const float*)d_in[4];
  const float* W1    = (const float*)d_in[5];
  const float* b1    = (const float*)d_in[6];
  const float* W2    = (const float*)d_in[7];
  // d_in[8] = b2 scalar: softmax is shift-invariant -> drops out exactly.
  char* ws = (char*)d_ws;   // needs ~2.74 MB
  float* out = (float*)d_out;

  k0_prep   <<<dim3(64),   dim3(256), 0, stream>>>(Wp, gamma, beta, W1, ws);
  k0_reduce <<<dim3(1),    dim3(256), 0, stream>>>(bproj, ws);
  k1_main   <<<dim3(2048), dim3(256), 0, stream>>>(x, b1, W2, ws);
  k2_combine<<<dim3(64),   dim3(256), 0, stream>>>(ws, out);
}